// Round 2
// baseline (5375.357 us; speedup 1.0000x reference)
//
#include <hip/hip_runtime.h>
#include <stdint.h>

typedef __bf16 bf16;
typedef __bf16 bf16x8 __attribute__((ext_vector_type(8)));
typedef __bf16 bf16x4 __attribute__((ext_vector_type(4)));
typedef float f32x4 __attribute__((ext_vector_type(4)));

static __device__ __forceinline__ float bflo(uint32_t u) { return __uint_as_float(u << 16); }
static __device__ __forceinline__ float bfhi(uint32_t u) { return __uint_as_float(u & 0xffff0000u); }

// ---------------- init / conversion ----------------

__global__ __launch_bounds__(256) void k_zero(int* __restrict__ cursor, float* __restrict__ stats,
                                              int n, int nstats) {
    int i = blockIdx.x * 256 + threadIdx.x;
    if (i < n) cursor[i] = 0;
    if (i < nstats) stats[i] = 0.f;
}

__global__ __launch_bounds__(256) void k_cvt_x(const float* __restrict__ x, bf16* __restrict__ h, int n4) {
    int i = blockIdx.x * 256 + threadIdx.x;
    if (i >= n4) return;
    float4 v = ((const float4*)x)[i];
    bf16x4 o = {(bf16)v.x, (bf16)v.y, (bf16)v.z, (bf16)v.w};
    *(bf16x4*)(h + 4 * (size_t)i) = o;
}

__global__ __launch_bounds__(256) void k_cvt_w(const float* __restrict__ wl, const float* __restrict__ wr,
                                               bf16* __restrict__ dst, int n) {
    int i = blockIdx.x * 256 + threadIdx.x;
    if (i >= n) return;
    dst[i] = (bf16)wl[i];
    dst[n + i] = (bf16)wr[i];
}

// ---------------- CSR build ----------------

__global__ __launch_bounds__(256) void k_count(const int* __restrict__ dst, int* __restrict__ deg, int E) {
    int e = blockIdx.x * 256 + threadIdx.x;
    if (e < E) atomicAdd(&deg[dst[e]], 1);
}

__global__ __launch_bounds__(256) void k_scan1(const int* __restrict__ deg, int* __restrict__ rowptr,
                                               int* __restrict__ bsum, int N) {
    __shared__ int sh[256];
    int i = blockIdx.x * 256 + threadIdx.x;
    int v = (i < N) ? deg[i] : 0;
    sh[threadIdx.x] = v;
    for (int off = 1; off < 256; off <<= 1) {
        __syncthreads();
        int t = (threadIdx.x >= off) ? sh[threadIdx.x - off] : 0;
        __syncthreads();
        sh[threadIdx.x] += t;
    }
    __syncthreads();
    if (i <= N) rowptr[i] = sh[threadIdx.x] - v;
    if (threadIdx.x == 255) bsum[blockIdx.x] = sh[255];
}

__global__ __launch_bounds__(512) void k_scan2(int* __restrict__ bsum, int nb) {
    __shared__ int sh[512];
    int v = (threadIdx.x < nb) ? bsum[threadIdx.x] : 0;
    sh[threadIdx.x] = v;
    for (int off = 1; off < 512; off <<= 1) {
        __syncthreads();
        int t = (threadIdx.x >= off) ? sh[threadIdx.x - off] : 0;
        __syncthreads();
        sh[threadIdx.x] += t;
    }
    __syncthreads();
    if (threadIdx.x < nb) bsum[threadIdx.x] = sh[threadIdx.x] - v;
}

__global__ __launch_bounds__(256) void k_scan3(int* __restrict__ rowptr, const int* __restrict__ bsum,
                                               int* __restrict__ cursor, int N) {
    int i = blockIdx.x * 256 + threadIdx.x;
    if (i <= N) {
        int v = rowptr[i] + bsum[i >> 8];
        rowptr[i] = v;
        if (i < N) cursor[i] = v;
    }
}

__global__ __launch_bounds__(256) void k_scatter(const int* __restrict__ src, const int* __restrict__ dst,
                                                 int* __restrict__ cursor, int* __restrict__ ssrc, int E) {
    int e = blockIdx.x * 256 + threadIdx.x;
    if (e < E) {
        int d = dst[e];
        int pos = atomicAdd(&cursor[d], 1);
        ssrc[pos] = src[e];
    }
}

// ---------------- GEMM: P = X@Wl^T (bf16), R = X@Wr^T + bl (f32) ----------------

__global__ __launch_bounds__(256) void k_gemm(const bf16* __restrict__ X, const bf16* __restrict__ W,
                                              const float* __restrict__ bl, bf16* __restrict__ P,
                                              float* __restrict__ R, int Cout, int N) {
    int wv = blockIdx.x * 4 + (threadIdx.x >> 6);
    int lane = threadIdx.x & 63;
    int node0 = wv * 16;
    if (node0 >= N) return;
    int m = lane & 15, quad = lane >> 4;
    const bf16* xr = X + (size_t)(node0 + m) * 128 + quad * 8;
    bf16x8 a0 = *(const bf16x8*)(xr);
    bf16x8 a1 = *(const bf16x8*)(xr + 32);
    bf16x8 a2 = *(const bf16x8*)(xr + 64);
    bf16x8 a3 = *(const bf16x8*)(xr + 96);
    int ntiles = (2 * Cout) >> 4;
    for (int ct = 0; ct < ntiles; ct++) {
        const bf16* wr = W + (size_t)(ct * 16 + m) * 128 + quad * 8;
        f32x4 acc = {0.f, 0.f, 0.f, 0.f};
        acc = __builtin_amdgcn_mfma_f32_16x16x32_bf16(a0, *(const bf16x8*)(wr), acc, 0, 0, 0);
        acc = __builtin_amdgcn_mfma_f32_16x16x32_bf16(a1, *(const bf16x8*)(wr + 32), acc, 0, 0, 0);
        acc = __builtin_amdgcn_mfma_f32_16x16x32_bf16(a2, *(const bf16x8*)(wr + 64), acc, 0, 0, 0);
        acc = __builtin_amdgcn_mfma_f32_16x16x32_bf16(a3, *(const bf16x8*)(wr + 96), acc, 0, 0, 0);
        int col = (ct << 4) + m;
        if (col < Cout) {
            bf16* pp = P + (size_t)(node0 + quad * 4) * Cout + col;
            pp[0] = (bf16)acc[0];
            pp[Cout] = (bf16)acc[1];
            pp[2 * Cout] = (bf16)acc[2];
            pp[3 * Cout] = (bf16)acc[3];
        } else {
            int c2 = col - Cout;
            float bb = bl[c2];
            float* rr = R + (size_t)(node0 + quad * 4) * Cout + c2;
            rr[0] = acc[0] + bb;
            rr[Cout] = acc[1] + bb;
            rr[2 * Cout] = acc[2] + bb;
            rr[3 * Cout] = acc[3] + bb;
        }
    }
}

// ---------------- aggregate ----------------
// Wave per node (grid-stride). C/8 lanes per edge, each lane one dwordx4 (8 bf16 cols),
// 64/(C/8) edges concurrently, unrolled x2 -> up to 2 gathers in flight per lane.
// Cross-group butterfly reduce, then group 0 does mean + root-add + BN stats.

template <int C>
__global__ __launch_bounds__(256) void k_agg(const bf16* __restrict__ p, const float* __restrict__ r,
                                             const int* __restrict__ rowptr, const int* __restrict__ ssrc,
                                             float* __restrict__ o, float* __restrict__ ssum,
                                             float* __restrict__ ssq, int N, int nwaves) {
    constexpr int LC = C / 8;     // lanes per edge
    constexpr int GRP = 64 / LC;  // edges in flight
    int wv = (blockIdx.x * 256 + threadIdx.x) >> 6;
    int lane = threadIdx.x & 63;
    int sub = lane % LC;
    int grp = lane / LC;
    float s[8] = {0.f, 0.f, 0.f, 0.f, 0.f, 0.f, 0.f, 0.f};
    float q[8] = {0.f, 0.f, 0.f, 0.f, 0.f, 0.f, 0.f, 0.f};
    const uint4* pb = (const uint4*)p;  // row = C/8 uint4s
    constexpr int RS = C / 8;
    for (int n = wv; n < N; n += nwaves) {
        int e0 = rowptr[n], e1 = rowptr[n + 1];
        float acc[8] = {0.f, 0.f, 0.f, 0.f, 0.f, 0.f, 0.f, 0.f};
        int e = e0 + grp;
        for (; e + GRP < e1; e += 2 * GRP) {
            int i0 = ssrc[e];
            int i1 = ssrc[e + GRP];
            uint4 u = pb[(size_t)i0 * RS + sub];
            uint4 v = pb[(size_t)i1 * RS + sub];
            acc[0] += bflo(u.x) + bflo(v.x);
            acc[1] += bfhi(u.x) + bfhi(v.x);
            acc[2] += bflo(u.y) + bflo(v.y);
            acc[3] += bfhi(u.y) + bfhi(v.y);
            acc[4] += bflo(u.z) + bflo(v.z);
            acc[5] += bfhi(u.z) + bfhi(v.z);
            acc[6] += bflo(u.w) + bflo(v.w);
            acc[7] += bfhi(u.w) + bfhi(v.w);
        }
        if (e < e1) {
            uint4 u = pb[(size_t)ssrc[e] * RS + sub];
            acc[0] += bflo(u.x);
            acc[1] += bfhi(u.x);
            acc[2] += bflo(u.y);
            acc[3] += bfhi(u.y);
            acc[4] += bflo(u.z);
            acc[5] += bfhi(u.z);
            acc[6] += bflo(u.w);
            acc[7] += bfhi(u.w);
        }
#pragma unroll
        for (int m = LC; m < 64; m <<= 1) {
#pragma unroll
            for (int j = 0; j < 8; j++) acc[j] += __shfl_xor(acc[j], m, 64);
        }
        if (grp == 0) {
            int d = e1 - e0;
            float sc = 1.0f / (float)(d > 0 ? d : 1);
            const float* rr = r + (size_t)n * C + sub * 8;
            float4 r0 = *(const float4*)rr;
            float4 r1 = *(const float4*)(rr + 4);
            float ov[8];
            ov[0] = fmaf(acc[0], sc, r0.x);
            ov[1] = fmaf(acc[1], sc, r0.y);
            ov[2] = fmaf(acc[2], sc, r0.z);
            ov[3] = fmaf(acc[3], sc, r0.w);
            ov[4] = fmaf(acc[4], sc, r1.x);
            ov[5] = fmaf(acc[5], sc, r1.y);
            ov[6] = fmaf(acc[6], sc, r1.z);
            ov[7] = fmaf(acc[7], sc, r1.w);
            float* oo = o + (size_t)n * C + sub * 8;
            *(float4*)oo = make_float4(ov[0], ov[1], ov[2], ov[3]);
            *(float4*)(oo + 4) = make_float4(ov[4], ov[5], ov[6], ov[7]);
#pragma unroll
            for (int j = 0; j < 8; j++) {
                s[j] += ov[j];
                q[j] += ov[j] * ov[j];
            }
        }
    }
    if (grp == 0) {
#pragma unroll
        for (int j = 0; j < 8; j++) {
            atomicAdd(&ssum[sub * 8 + j], s[j]);
            atomicAdd(&ssq[sub * 8 + j], q[j]);
        }
    }
}

// ---------------- BN finalize + normalize ----------------

__global__ __launch_bounds__(128) void k_bn_fin(const float* __restrict__ ssum, const float* __restrict__ ssq,
                                                const float* __restrict__ gamma, const float* __restrict__ beta,
                                                float* __restrict__ cA, float* __restrict__ cB, int Cout, int N) {
    int c = threadIdx.x;
    if (c >= Cout) return;
    float m = ssum[c] / (float)N;
    float var = ssq[c] / (float)N - m * m;
    float a = gamma[c] * rsqrtf(var + 1e-5f);
    cA[c] = a;
    cB[c] = beta[c] - m * a;
}

__global__ __launch_bounds__(256) void k_norm_relu(const float* __restrict__ o, const float* __restrict__ cA,
                                                   const float* __restrict__ cB, bf16* __restrict__ h, int n4) {
    int i = blockIdx.x * 256 + threadIdx.x;
    if (i >= n4) return;
    float4 v = ((const float4*)o)[i];
    int c = (i * 4) & 127;
    float4 a = *(const float4*)(cA + c);
    float4 b = *(const float4*)(cB + c);
    float r0 = fmaxf(fmaf(v.x, a.x, b.x), 0.f);
    float r1 = fmaxf(fmaf(v.y, a.y, b.y), 0.f);
    float r2 = fmaxf(fmaf(v.z, a.z, b.z), 0.f);
    float r3 = fmaxf(fmaf(v.w, a.w, b.w), 0.f);
    bf16x4 ov = {(bf16)r0, (bf16)r1, (bf16)r2, (bf16)r3};
    *(bf16x4*)(h + 4 * (size_t)i) = ov;
}

__global__ __launch_bounds__(256) void k_norm_out(const float* __restrict__ o, const float* __restrict__ cA,
                                                  const float* __restrict__ cB, float* __restrict__ out, int n4) {
    int i = blockIdx.x * 256 + threadIdx.x;
    if (i >= n4) return;
    float4 v = ((const float4*)o)[i];
    int c = (i * 4) & 63;
    float4 a = *(const float4*)(cA + c);
    float4 b = *(const float4*)(cB + c);
    float4 ov;
    ov.x = fmaf(v.x, a.x, b.x);
    ov.y = fmaf(v.y, a.y, b.y);
    ov.z = fmaf(v.z, a.z, b.z);
    ov.w = fmaf(v.w, a.w, b.w);
    ((float4*)out)[i] = ov;
}

// ---------------- launch ----------------

static inline int cdiv(int a, int b) { return (a + b - 1) / b; }

extern "C" void kernel_launch(void* const* d_in, const int* in_sizes, int n_in,
                              void* d_out, int out_size, void* d_ws, size_t ws_size,
                              hipStream_t stream) {
    const float* x = (const float*)d_in[0];
    const int* ei = (const int*)d_in[1];
    const float* Wl[3] = {(const float*)d_in[2], (const float*)d_in[7], (const float*)d_in[12]};
    const float* bl[3] = {(const float*)d_in[3], (const float*)d_in[8], (const float*)d_in[13]};
    const float* Wr[3] = {(const float*)d_in[4], (const float*)d_in[9], (const float*)d_in[14]};
    const float* gam[3] = {(const float*)d_in[5], (const float*)d_in[10], (const float*)d_in[15]};
    const float* bet[3] = {(const float*)d_in[6], (const float*)d_in[11], (const float*)d_in[16]};

    const int N = in_sizes[0] / 128;  // 100000
    const int E = in_sizes[1] / 2;    // 1600000
    const int Couts[3] = {128, 128, 64};

    char* base = (char*)d_ws;
    size_t off = 0;
    auto alloc = [&](size_t bytes) -> void* {
        void* ptr = base + off;
        off += (bytes + 255) & ~(size_t)255;
        return ptr;
    };
    bf16* h = (bf16*)alloc((size_t)N * 128 * 2);
    bf16* p = (bf16*)alloc((size_t)N * 128 * 2);
    float* r = (float*)alloc((size_t)N * 128 * 4);
    float* o = (float*)alloc((size_t)N * 128 * 4);
    bf16* w0 = (bf16*)alloc(2 * 128 * 128 * 2);
    bf16* w1 = (bf16*)alloc(2 * 128 * 128 * 2);
    bf16* w2 = (bf16*)alloc(2 * 64 * 128 * 2);
    float* stats = (float*)alloc(3 * 512 * 4);
    int* rowptr = (int*)alloc((size_t)(N + 1) * 4);
    int* cursor = (int*)alloc((size_t)N * 4);
    int* bsum = (int*)alloc(512 * 4);
    int* ssrc = (int*)alloc((size_t)E * 4);
    bf16* Wc[3] = {w0, w1, w2};

    const int* esrc = ei;
    const int* edst = ei + E;

    k_zero<<<cdiv(N, 256), 256, 0, stream>>>(cursor, stats, N, 3 * 512);
    k_cvt_x<<<cdiv(N * 32, 256), 256, 0, stream>>>(x, h, N * 32);
    k_cvt_w<<<cdiv(128 * 128, 256), 256, 0, stream>>>(Wl[0], Wr[0], w0, 128 * 128);
    k_cvt_w<<<cdiv(128 * 128, 256), 256, 0, stream>>>(Wl[1], Wr[1], w1, 128 * 128);
    k_cvt_w<<<cdiv(64 * 128, 256), 256, 0, stream>>>(Wl[2], Wr[2], w2, 64 * 128);

    k_count<<<cdiv(E, 256), 256, 0, stream>>>(edst, cursor, E);
    int nb = cdiv(N + 1, 256);
    k_scan1<<<nb, 256, 0, stream>>>(cursor, rowptr, bsum, N);
    k_scan2<<<1, 512, 0, stream>>>(bsum, nb);
    k_scan3<<<nb, 256, 0, stream>>>(rowptr, bsum, cursor, N);
    k_scatter<<<cdiv(E, 256), 256, 0, stream>>>(esrc, edst, cursor, ssrc, E);

    const int AGG_BLOCKS = 2048;
    const int NWAVES = AGG_BLOCKS * 4;
    for (int l = 0; l < 3; l++) {
        int Cout = Couts[l];
        float* ss = stats + l * 512;
        float* sq = ss + 128;
        float* cA = ss + 256;
        float* cB = ss + 384;
        k_gemm<<<cdiv(N / 16, 4), 256, 0, stream>>>(h, Wc[l], bl[l], p, r, Cout, N);
        if (Cout == 128) {
            k_agg<128><<<AGG_BLOCKS, 256, 0, stream>>>(p, r, rowptr, ssrc, o, ss, sq, N, NWAVES);
        } else {
            k_agg<64><<<AGG_BLOCKS, 256, 0, stream>>>(p, r, rowptr, ssrc, o, ss, sq, N, NWAVES);
        }
        k_bn_fin<<<1, 128, 0, stream>>>(ss, sq, gam[l], bet[l], cA, cB, Cout, N);
        if (l < 2) {
            k_norm_relu<<<cdiv(N * 32, 256), 256, 0, stream>>>(o, cA, cB, h, N * 32);
        } else {
            k_norm_out<<<cdiv(N * 16, 256), 256, 0, stream>>>(o, cA, cB, (float*)d_out, N * 16);
        }
    }
}

// Round 3
// 1107.982 us; speedup vs baseline: 4.8515x; 4.8515x over previous
//
#include <hip/hip_runtime.h>
#include <stdint.h>

typedef __bf16 bf16;
typedef __bf16 bf16x8 __attribute__((ext_vector_type(8)));
typedef __bf16 bf16x4 __attribute__((ext_vector_type(4)));
typedef float f32x4 __attribute__((ext_vector_type(4)));

static __device__ __forceinline__ float bflo(uint32_t u) { return __uint_as_float(u << 16); }
static __device__ __forceinline__ float bfhi(uint32_t u) { return __uint_as_float(u & 0xffff0000u); }

// ---------------- init / conversion ----------------

__global__ __launch_bounds__(256) void k_zero(int* __restrict__ cursor, float* __restrict__ stats,
                                              int n, int nstats) {
    int i = blockIdx.x * 256 + threadIdx.x;
    if (i < n) cursor[i] = 0;
    if (i < nstats) stats[i] = 0.f;
}

__global__ __launch_bounds__(256) void k_cvt_x(const float* __restrict__ x, bf16* __restrict__ h, int n4) {
    int i = blockIdx.x * 256 + threadIdx.x;
    if (i >= n4) return;
    float4 v = ((const float4*)x)[i];
    bf16x4 o = {(bf16)v.x, (bf16)v.y, (bf16)v.z, (bf16)v.w};
    *(bf16x4*)(h + 4 * (size_t)i) = o;
}

__global__ __launch_bounds__(256) void k_cvt_w(const float* __restrict__ wl, const float* __restrict__ wr,
                                               bf16* __restrict__ dst, int n) {
    int i = blockIdx.x * 256 + threadIdx.x;
    if (i >= n) return;
    dst[i] = (bf16)wl[i];
    dst[n + i] = (bf16)wr[i];
}

// ---------------- CSR build ----------------

__global__ __launch_bounds__(256) void k_count(const int* __restrict__ dst, int* __restrict__ deg, int E) {
    int e = blockIdx.x * 256 + threadIdx.x;
    if (e < E) atomicAdd(&deg[dst[e]], 1);
}

__global__ __launch_bounds__(256) void k_scan1(const int* __restrict__ deg, int* __restrict__ rowptr,
                                               int* __restrict__ bsum, int N) {
    __shared__ int sh[256];
    int i = blockIdx.x * 256 + threadIdx.x;
    int v = (i < N) ? deg[i] : 0;
    sh[threadIdx.x] = v;
    for (int off = 1; off < 256; off <<= 1) {
        __syncthreads();
        int t = (threadIdx.x >= off) ? sh[threadIdx.x - off] : 0;
        __syncthreads();
        sh[threadIdx.x] += t;
    }
    __syncthreads();
    if (i <= N) rowptr[i] = sh[threadIdx.x] - v;
    if (threadIdx.x == 255) bsum[blockIdx.x] = sh[255];
}

__global__ __launch_bounds__(512) void k_scan2(int* __restrict__ bsum, int nb) {
    __shared__ int sh[512];
    int v = (threadIdx.x < nb) ? bsum[threadIdx.x] : 0;
    sh[threadIdx.x] = v;
    for (int off = 1; off < 512; off <<= 1) {
        __syncthreads();
        int t = (threadIdx.x >= off) ? sh[threadIdx.x - off] : 0;
        __syncthreads();
        sh[threadIdx.x] += t;
    }
    __syncthreads();
    if (threadIdx.x < nb) bsum[threadIdx.x] = sh[threadIdx.x] - v;
}

__global__ __launch_bounds__(256) void k_scan3(int* __restrict__ rowptr, const int* __restrict__ bsum,
                                               int* __restrict__ cursor, int N) {
    int i = blockIdx.x * 256 + threadIdx.x;
    if (i <= N) {
        int v = rowptr[i] + bsum[i >> 8];
        rowptr[i] = v;
        if (i < N) cursor[i] = v;
    }
}

__global__ __launch_bounds__(256) void k_scatter(const int* __restrict__ src, const int* __restrict__ dst,
                                                 int* __restrict__ cursor, int* __restrict__ ssrc, int E) {
    int e = blockIdx.x * 256 + threadIdx.x;
    if (e < E) {
        int d = dst[e];
        int pos = atomicAdd(&cursor[d], 1);
        ssrc[pos] = src[e];
    }
}

// ---------------- GEMM: P = X@Wl^T (bf16, col-tiled), R = X@Wr^T + bl (f32, col-tiled) ----------------
// Output layout: P_t[g][n][16] bf16 (g = col/16), R_t[g][n][16] f32.

__global__ __launch_bounds__(256) void k_gemm(const bf16* __restrict__ X, const bf16* __restrict__ W,
                                              const float* __restrict__ bl, bf16* __restrict__ P,
                                              float* __restrict__ R, int Cout, int N) {
    int wv = blockIdx.x * 4 + (threadIdx.x >> 6);
    int lane = threadIdx.x & 63;
    int node0 = wv * 16;
    if (node0 >= N) return;
    int m = lane & 15, quad = lane >> 4;
    const bf16* xr = X + (size_t)(node0 + m) * 128 + quad * 8;
    bf16x8 a0 = *(const bf16x8*)(xr);
    bf16x8 a1 = *(const bf16x8*)(xr + 32);
    bf16x8 a2 = *(const bf16x8*)(xr + 64);
    bf16x8 a3 = *(const bf16x8*)(xr + 96);
    int ntiles = (2 * Cout) >> 4;
    int ntilesP = Cout >> 4;
    for (int ct = 0; ct < ntiles; ct++) {
        const bf16* wr = W + (size_t)(ct * 16 + m) * 128 + quad * 8;
        f32x4 acc = {0.f, 0.f, 0.f, 0.f};
        acc = __builtin_amdgcn_mfma_f32_16x16x32_bf16(a0, *(const bf16x8*)(wr), acc, 0, 0, 0);
        acc = __builtin_amdgcn_mfma_f32_16x16x32_bf16(a1, *(const bf16x8*)(wr + 32), acc, 0, 0, 0);
        acc = __builtin_amdgcn_mfma_f32_16x16x32_bf16(a2, *(const bf16x8*)(wr + 64), acc, 0, 0, 0);
        acc = __builtin_amdgcn_mfma_f32_16x16x32_bf16(a3, *(const bf16x8*)(wr + 96), acc, 0, 0, 0);
        // D mapping: col = ct*16 + m, node = node0 + quad*4 + reg
        if (ct < ntilesP) {
            bf16* pp = P + (size_t)ct * N * 16 + (size_t)(node0 + quad * 4) * 16 + m;
            pp[0] = (bf16)acc[0];
            pp[16] = (bf16)acc[1];
            pp[32] = (bf16)acc[2];
            pp[48] = (bf16)acc[3];
        } else {
            int gt = ct - ntilesP;
            float bb = bl[gt * 16 + m];
            float* rr = R + (size_t)gt * N * 16 + (size_t)(node0 + quad * 4) * 16 + m;
            rr[0] = acc[0] + bb;
            rr[16] = acc[1] + bb;
            rr[32] = acc[2] + bb;
            rr[48] = acc[3] + bb;
        }
    }
}

// ---------------- aggregate (XCD-sharded col-tiled) ----------------
// blockIdx%8 -> XCD g; col-group cg = g%NG (slice of 16 cols, 3.2MB -> fits 4MB L2).
// Per edge: 8 lanes x dword (2 bf16 cols). 8 edges per instruction, unroll x2.
// Butterfly reduce over lane-groups, group 0 (8 lanes) finalizes mean+root+stats.

template <int NG>
__global__ __launch_bounds__(256) void k_agg(const bf16* __restrict__ p, const float* __restrict__ r,
                                             const int* __restrict__ rowptr, const int* __restrict__ ssrc,
                                             float* __restrict__ o, float* __restrict__ ssum,
                                             float* __restrict__ ssq, int N) {
    int g = blockIdx.x & 7;
    int cg = g % NG;
    int rep = g / NG;
    constexpr int NREP = 8 / NG;
    int brank = (blockIdx.x >> 3) * NREP + rep;
    int wvg = brank * 4 + (threadIdx.x >> 6);
    int nwv = (gridDim.x >> 3) * NREP * 4;
    wvg = __builtin_amdgcn_readfirstlane(wvg);
    int lane = threadIdx.x & 63;
    int sub = lane & 7;   // dword within 32B row-slice (2 cols)
    int grp = lane >> 3;  // which of 8 concurrent edges
    const uint32_t* pu = (const uint32_t*)(p + (size_t)cg * N * 16);  // row = 8 dwords
    const float* rt = r + (size_t)cg * N * 16;
    float* ot = o + (size_t)cg * N * 16;
    float s0 = 0.f, s1 = 0.f, q0 = 0.f, q1 = 0.f;
    for (int n = wvg; n < N; n += nwv) {
        int e0 = rowptr[n], e1 = rowptr[n + 1];
        float a0 = 0.f, a1 = 0.f;
        int e = e0 + grp;
        for (; e + 8 < e1; e += 16) {
            int i0 = ssrc[e];
            int i1 = ssrc[e + 8];
            uint32_t u = pu[i0 * 8 + sub];
            uint32_t v = pu[i1 * 8 + sub];
            a0 += bflo(u) + bflo(v);
            a1 += bfhi(u) + bfhi(v);
        }
        if (e < e1) {
            uint32_t u = pu[ssrc[e] * 8 + sub];
            a0 += bflo(u);
            a1 += bfhi(u);
        }
#pragma unroll
        for (int msk = 8; msk < 64; msk <<= 1) {
            a0 += __shfl_xor(a0, msk, 64);
            a1 += __shfl_xor(a1, msk, 64);
        }
        if (grp == 0) {
            int d = e1 - e0;
            float sc = 1.0f / (float)(d > 0 ? d : 1);
            float2 rv = *(const float2*)(rt + (size_t)n * 16 + sub * 2);
            float o0 = fmaf(a0, sc, rv.x);
            float o1 = fmaf(a1, sc, rv.y);
            float2 ov = make_float2(o0, o1);
            *(float2*)(ot + (size_t)n * 16 + sub * 2) = ov;
            s0 += o0;
            s1 += o1;
            q0 += o0 * o0;
            q1 += o1 * o1;
        }
    }
    if (grp == 0) {
        int c = cg * 16 + sub * 2;
        atomicAdd(&ssum[c], s0);
        atomicAdd(&ssum[c + 1], s1);
        atomicAdd(&ssq[c], q0);
        atomicAdd(&ssq[c + 1], q1);
    }
}

// ---------------- BN finalize + normalize ----------------

__global__ __launch_bounds__(128) void k_bn_fin(const float* __restrict__ ssum, const float* __restrict__ ssq,
                                                const float* __restrict__ gamma, const float* __restrict__ beta,
                                                float* __restrict__ cA, float* __restrict__ cB, int Cout, int N) {
    int c = threadIdx.x;
    if (c >= Cout) return;
    float m = ssum[c] / (float)N;
    float var = ssq[c] / (float)N - m * m;
    float a = gamma[c] * rsqrtf(var + 1e-5f);
    cA[c] = a;
    cB[c] = beta[c] - m * a;
}

// o_t (col-tiled f32) -> h (row-major bf16), relu. grid.y = col group.
__global__ __launch_bounds__(256) void k_norm_relu(const float* __restrict__ o, const float* __restrict__ cA,
                                                   const float* __restrict__ cB, bf16* __restrict__ h, int N) {
    int i = blockIdx.x * 256 + threadIdx.x;
    if (i >= N * 4) return;
    int g = blockIdx.y;
    float4 v = *(const float4*)(o + (size_t)g * N * 16 + (size_t)i * 4);
    int n = i >> 2;
    int col = g * 16 + (i & 3) * 4;
    float4 a = *(const float4*)(cA + col);
    float4 b = *(const float4*)(cB + col);
    float r0 = fmaxf(fmaf(v.x, a.x, b.x), 0.f);
    float r1 = fmaxf(fmaf(v.y, a.y, b.y), 0.f);
    float r2 = fmaxf(fmaf(v.z, a.z, b.z), 0.f);
    float r3 = fmaxf(fmaf(v.w, a.w, b.w), 0.f);
    bf16x4 ov = {(bf16)r0, (bf16)r1, (bf16)r2, (bf16)r3};
    *(bf16x4*)(h + (size_t)n * 128 + col) = ov;
}

// o_t (col-tiled f32, NG=4) -> out (row-major f32, C=64), no relu.
__global__ __launch_bounds__(256) void k_norm_out(const float* __restrict__ o, const float* __restrict__ cA,
                                                  const float* __restrict__ cB, float* __restrict__ out, int N) {
    int i = blockIdx.x * 256 + threadIdx.x;
    if (i >= N * 4) return;
    int g = blockIdx.y;
    float4 v = *(const float4*)(o + (size_t)g * N * 16 + (size_t)i * 4);
    int n = i >> 2;
    int col = g * 16 + (i & 3) * 4;
    float4 a = *(const float4*)(cA + col);
    float4 b = *(const float4*)(cB + col);
    float4 ov;
    ov.x = fmaf(v.x, a.x, b.x);
    ov.y = fmaf(v.y, a.y, b.y);
    ov.z = fmaf(v.z, a.z, b.z);
    ov.w = fmaf(v.w, a.w, b.w);
    *(float4*)(out + (size_t)n * 64 + col) = ov;
}

// ---------------- launch ----------------

static inline int cdiv(int a, int b) { return (a + b - 1) / b; }

extern "C" void kernel_launch(void* const* d_in, const int* in_sizes, int n_in,
                              void* d_out, int out_size, void* d_ws, size_t ws_size,
                              hipStream_t stream) {
    const float* x = (const float*)d_in[0];
    const int* ei = (const int*)d_in[1];
    const float* Wl[3] = {(const float*)d_in[2], (const float*)d_in[7], (const float*)d_in[12]};
    const float* bl[3] = {(const float*)d_in[3], (const float*)d_in[8], (const float*)d_in[13]};
    const float* Wr[3] = {(const float*)d_in[4], (const float*)d_in[9], (const float*)d_in[14]};
    const float* gam[3] = {(const float*)d_in[5], (const float*)d_in[10], (const float*)d_in[15]};
    const float* bet[3] = {(const float*)d_in[6], (const float*)d_in[11], (const float*)d_in[16]};

    const int N = in_sizes[0] / 128;  // 100000
    const int E = in_sizes[1] / 2;    // 1600000
    const int Couts[3] = {128, 128, 64};

    char* base = (char*)d_ws;
    size_t off = 0;
    auto alloc = [&](size_t bytes) -> void* {
        void* ptr = base + off;
        off += (bytes + 255) & ~(size_t)255;
        return ptr;
    };
    bf16* h = (bf16*)alloc((size_t)N * 128 * 2);
    bf16* p = (bf16*)alloc((size_t)N * 128 * 2);
    float* r = (float*)alloc((size_t)N * 128 * 4);
    float* o = (float*)alloc((size_t)N * 128 * 4);
    bf16* w0 = (bf16*)alloc(2 * 128 * 128 * 2);
    bf16* w1 = (bf16*)alloc(2 * 128 * 128 * 2);
    bf16* w2 = (bf16*)alloc(2 * 64 * 128 * 2);
    float* stats = (float*)alloc(3 * 512 * 4);
    int* rowptr = (int*)alloc((size_t)(N + 1) * 4);
    int* cursor = (int*)alloc((size_t)N * 4);
    int* bsum = (int*)alloc(512 * 4);
    int* ssrc = (int*)alloc((size_t)E * 4);
    bf16* Wc[3] = {w0, w1, w2};

    const int* esrc = ei;
    const int* edst = ei + E;

    k_zero<<<cdiv(N, 256), 256, 0, stream>>>(cursor, stats, N, 3 * 512);
    k_cvt_x<<<cdiv(N * 32, 256), 256, 0, stream>>>(x, h, N * 32);
    k_cvt_w<<<cdiv(128 * 128, 256), 256, 0, stream>>>(Wl[0], Wr[0], w0, 128 * 128);
    k_cvt_w<<<cdiv(128 * 128, 256), 256, 0, stream>>>(Wl[1], Wr[1], w1, 128 * 128);
    k_cvt_w<<<cdiv(64 * 128, 256), 256, 0, stream>>>(Wl[2], Wr[2], w2, 64 * 128);

    k_count<<<cdiv(E, 256), 256, 0, stream>>>(edst, cursor, E);
    int nb = cdiv(N + 1, 256);
    k_scan1<<<nb, 256, 0, stream>>>(cursor, rowptr, bsum, N);
    k_scan2<<<1, 512, 0, stream>>>(bsum, nb);
    k_scan3<<<nb, 256, 0, stream>>>(rowptr, bsum, cursor, N);
    k_scatter<<<cdiv(E, 256), 256, 0, stream>>>(esrc, edst, cursor, ssrc, E);

    const int AGG_BLOCKS = 2048;
    for (int l = 0; l < 3; l++) {
        int Cout = Couts[l];
        float* ss = stats + l * 512;
        float* sq = ss + 128;
        float* cA = ss + 256;
        float* cB = ss + 384;
        k_gemm<<<cdiv(N / 16, 4), 256, 0, stream>>>(h, Wc[l], bl[l], p, r, Cout, N);
        if (Cout == 128) {
            k_agg<8><<<AGG_BLOCKS, 256, 0, stream>>>(p, r, rowptr, ssrc, o, ss, sq, N);
        } else {
            k_agg<4><<<AGG_BLOCKS, 256, 0, stream>>>(p, r, rowptr, ssrc, o, ss, sq, N);
        }
        k_bn_fin<<<1, 128, 0, stream>>>(ss, sq, gam[l], bet[l], cA, cB, Cout, N);
        if (l < 2) {
            dim3 gnr(cdiv(N * 4, 256), 8);
            k_norm_relu<<<gnr, 256, 0, stream>>>(o, cA, cB, h, N);
        } else {
            dim3 gno(cdiv(N * 4, 256), 4);
            k_norm_out<<<gno, 256, 0, stream>>>(o, cA, cB, (float*)d_out, N);
        }
    }
}

// Round 4
// 835.150 us; speedup vs baseline: 6.4364x; 1.3267x over previous
//
#include <hip/hip_runtime.h>
#include <stdint.h>

typedef __bf16 bf16;
typedef __bf16 bf16x8 __attribute__((ext_vector_type(8)));
typedef __bf16 bf16x4 __attribute__((ext_vector_type(4)));
typedef __bf16 bf16x2 __attribute__((ext_vector_type(2)));
typedef float f32x4 __attribute__((ext_vector_type(4)));

static __device__ __forceinline__ float bflo(uint32_t u) { return __uint_as_float(u << 16); }
static __device__ __forceinline__ float bfhi(uint32_t u) { return __uint_as_float(u & 0xffff0000u); }

// ---------------- init ----------------
// zero deg + stats + p zero-rows; prefill ssrc with pad index N.

__global__ __launch_bounds__(256) void k_init(int* __restrict__ deg, float* __restrict__ stats,
                                              bf16* __restrict__ p, int* __restrict__ ssrc,
                                              int N, int NP, int Ecap) {
    int i = blockIdx.x * 256 + threadIdx.x;
    if (i < N) deg[i] = 0;
    if (i < 3 * 512) stats[i] = 0.f;
    if (i < Ecap) ssrc[i] = N;  // pad -> zero row
    if (i < 128) {
        int g = i >> 4, c = i & 15;
        p[(size_t)g * NP * 16 + (size_t)N * 16 + c] = (bf16)0.f;
    }
}

__global__ __launch_bounds__(256) void k_cvt_w(const float* __restrict__ wl, const float* __restrict__ wr,
                                               bf16* __restrict__ dst, int n) {
    int i = blockIdx.x * 256 + threadIdx.x;
    if (i >= n) return;
    dst[i] = (bf16)wl[i];
    dst[n + i] = (bf16)wr[i];
}

// ---------------- CSR build (padded to multiples of 8) ----------------

__global__ __launch_bounds__(256) void k_count(const int* __restrict__ dst, int* __restrict__ deg, int E) {
    int e = blockIdx.x * 256 + threadIdx.x;
    if (e < E) atomicAdd(&deg[dst[e]], 1);
}

__global__ __launch_bounds__(256) void k_scan1(const int* __restrict__ deg, int* __restrict__ rowptr,
                                               int* __restrict__ bsum, int N) {
    __shared__ int sh[256];
    int i = blockIdx.x * 256 + threadIdx.x;
    int v = (i < N) ? ((deg[i] + 7) & ~7) : 0;
    sh[threadIdx.x] = v;
    for (int off = 1; off < 256; off <<= 1) {
        __syncthreads();
        int t = (threadIdx.x >= off) ? sh[threadIdx.x - off] : 0;
        __syncthreads();
        sh[threadIdx.x] += t;
    }
    __syncthreads();
    if (i <= N) rowptr[i] = sh[threadIdx.x] - v;
    if (threadIdx.x == 255) bsum[blockIdx.x] = sh[255];
}

__global__ __launch_bounds__(512) void k_scan2(int* __restrict__ bsum, int nb) {
    __shared__ int sh[512];
    int v = (threadIdx.x < nb) ? bsum[threadIdx.x] : 0;
    sh[threadIdx.x] = v;
    for (int off = 1; off < 512; off <<= 1) {
        __syncthreads();
        int t = (threadIdx.x >= off) ? sh[threadIdx.x - off] : 0;
        __syncthreads();
        sh[threadIdx.x] += t;
    }
    __syncthreads();
    if (threadIdx.x < nb) bsum[threadIdx.x] = sh[threadIdx.x] - v;
}

__global__ __launch_bounds__(256) void k_scan3(int* __restrict__ rowptr, const int* __restrict__ bsum,
                                               int* __restrict__ cursor, int N) {
    int i = blockIdx.x * 256 + threadIdx.x;
    if (i <= N) {
        int v = rowptr[i] + bsum[i >> 8];
        rowptr[i] = v;
        if (i < N) cursor[i] = v;
    }
}

__global__ __launch_bounds__(256) void k_scatter(const int* __restrict__ src, const int* __restrict__ dst,
                                                 int* __restrict__ cursor, int* __restrict__ ssrc, int E) {
    int e = blockIdx.x * 256 + threadIdx.x;
    if (e < E) {
        int d = dst[e];
        int pos = atomicAdd(&cursor[d], 1);
        ssrc[pos] = src[e];
    }
}

// ---------------- fused GEMM ----------------
// MODE 0: A = x (f32 row-major). MODE 1: A = relu(o*cA+cB), o bf16 col-tiled.
// Out: P_t[g][NP][16] bf16, R_t[g][N][16] bf16 (= X@Wr^T + bl).

template <int MODE>
__global__ __launch_bounds__(256) void k_gemm(const void* __restrict__ srcv, const float* __restrict__ cA,
                                              const float* __restrict__ cB, const bf16* __restrict__ W,
                                              const float* __restrict__ bl, bf16* __restrict__ P,
                                              bf16* __restrict__ R, int Cout, int N, int NP) {
    int wv = blockIdx.x * 4 + (threadIdx.x >> 6);
    int lane = threadIdx.x & 63;
    int node0 = wv * 16;
    if (node0 >= N) return;
    int m = lane & 15, quad = lane >> 4;
    bf16x8 a[4];
    if (MODE == 0) {
        const float* x = (const float*)srcv;
        const float* xr = x + (size_t)(node0 + m) * 128 + quad * 8;
#pragma unroll
        for (int t = 0; t < 4; t++) {
            float4 v0 = *(const float4*)(xr + t * 32);
            float4 v1 = *(const float4*)(xr + t * 32 + 4);
            bf16x8 f = {(bf16)v0.x, (bf16)v0.y, (bf16)v0.z, (bf16)v0.w,
                        (bf16)v1.x, (bf16)v1.y, (bf16)v1.z, (bf16)v1.w};
            a[t] = f;
        }
    } else {
        const bf16* o = (const bf16*)srcv;
#pragma unroll
        for (int t = 0; t < 4; t++) {
            int col0 = t * 32 + quad * 8;
            int g = col0 >> 4;
            int offs = col0 & 15;
            bf16x8 u = *(const bf16x8*)(o + (size_t)g * N * 16 + (size_t)(node0 + m) * 16 + offs);
            float4 ca0 = *(const float4*)(cA + col0);
            float4 ca1 = *(const float4*)(cA + col0 + 4);
            float4 cb0 = *(const float4*)(cB + col0);
            float4 cb1 = *(const float4*)(cB + col0 + 4);
            float h0 = fmaxf(fmaf((float)u[0], ca0.x, cb0.x), 0.f);
            float h1 = fmaxf(fmaf((float)u[1], ca0.y, cb0.y), 0.f);
            float h2 = fmaxf(fmaf((float)u[2], ca0.z, cb0.z), 0.f);
            float h3 = fmaxf(fmaf((float)u[3], ca0.w, cb0.w), 0.f);
            float h4 = fmaxf(fmaf((float)u[4], ca1.x, cb1.x), 0.f);
            float h5 = fmaxf(fmaf((float)u[5], ca1.y, cb1.y), 0.f);
            float h6 = fmaxf(fmaf((float)u[6], ca1.z, cb1.z), 0.f);
            float h7 = fmaxf(fmaf((float)u[7], ca1.w, cb1.w), 0.f);
            bf16x8 f = {(bf16)h0, (bf16)h1, (bf16)h2, (bf16)h3,
                        (bf16)h4, (bf16)h5, (bf16)h6, (bf16)h7};
            a[t] = f;
        }
    }
    int ntiles = (2 * Cout) >> 4;
    int ntilesP = Cout >> 4;
    for (int ct = 0; ct < ntiles; ct++) {
        const bf16* wr = W + (size_t)(ct * 16 + m) * 128 + quad * 8;
        f32x4 acc = {0.f, 0.f, 0.f, 0.f};
        acc = __builtin_amdgcn_mfma_f32_16x16x32_bf16(a[0], *(const bf16x8*)(wr), acc, 0, 0, 0);
        acc = __builtin_amdgcn_mfma_f32_16x16x32_bf16(a[1], *(const bf16x8*)(wr + 32), acc, 0, 0, 0);
        acc = __builtin_amdgcn_mfma_f32_16x16x32_bf16(a[2], *(const bf16x8*)(wr + 64), acc, 0, 0, 0);
        acc = __builtin_amdgcn_mfma_f32_16x16x32_bf16(a[3], *(const bf16x8*)(wr + 96), acc, 0, 0, 0);
        // D mapping: col = ct*16 + m, node = node0 + quad*4 + reg
        if (ct < ntilesP) {
            bf16* pp = P + (size_t)ct * NP * 16 + (size_t)(node0 + quad * 4) * 16 + m;
            pp[0] = (bf16)acc[0];
            pp[16] = (bf16)acc[1];
            pp[32] = (bf16)acc[2];
            pp[48] = (bf16)acc[3];
        } else {
            int gt = ct - ntilesP;
            float bb = bl[gt * 16 + m];
            bf16* rr = R + (size_t)gt * N * 16 + (size_t)(node0 + quad * 4) * 16 + m;
            rr[0] = (bf16)(acc[0] + bb);
            rr[16] = (bf16)(acc[1] + bb);
            rr[32] = (bf16)(acc[2] + bb);
            rr[48] = (bf16)(acc[3] + bb);
        }
    }
}

// ---------------- aggregate (XCD-sharded, node-per-group, padded CSR) ----------------
// blockIdx%8 -> XCD; cg = col group (16 cols = 8 dwords). Wave = 8 nodes (one per
// 8-lane group); lane owns 2 cols; edge loop 8-deep (pads hit zero row N).

template <int NG>
__global__ __launch_bounds__(256) void k_agg(const bf16* __restrict__ p, const bf16* __restrict__ r,
                                             const int* __restrict__ rowptr, const int* __restrict__ deg,
                                             const int* __restrict__ ssrc, bf16* __restrict__ o,
                                             float* __restrict__ ssum, float* __restrict__ ssq,
                                             int N, int NP) {
    int g = blockIdx.x & 7;
    int cg = g % NG;
    constexpr int NREP = 8 / NG;
    int rep = g / NG;
    int wvr = ((blockIdx.x >> 3) * NREP + rep) * 4 + (threadIdx.x >> 6);
    int nwv = (gridDim.x >> 3) * NREP * 4;
    int lane = threadIdx.x & 63;
    int sub = lane & 7;
    int grp = lane >> 3;
    const uint32_t* pu = (const uint32_t*)(p + (size_t)cg * NP * 16);
    const uint32_t* ru = (const uint32_t*)(r + (size_t)cg * N * 16);
    bf16* ot = o + (size_t)cg * N * 16;
    float s0 = 0.f, s1 = 0.f, q0 = 0.f, q1 = 0.f;
    int nchunk = (N + 7) >> 3;
    for (int c = wvr; c < nchunk; c += nwv) {
        int n = c * 8 + grp;
        bool valid = n < N;
        int e = 0, e1 = 0, d = 0;
        if (valid) {
            e = rowptr[n];
            e1 = rowptr[n + 1];
            d = deg[n];
        }
        float a0 = 0.f, a1 = 0.f;
        for (; e < e1; e += 8) {
            int i0 = ssrc[e], i1 = ssrc[e + 1], i2 = ssrc[e + 2], i3 = ssrc[e + 3];
            int i4 = ssrc[e + 4], i5 = ssrc[e + 5], i6 = ssrc[e + 6], i7 = ssrc[e + 7];
            uint32_t u0 = pu[(size_t)i0 * 8 + sub];
            uint32_t u1 = pu[(size_t)i1 * 8 + sub];
            uint32_t u2 = pu[(size_t)i2 * 8 + sub];
            uint32_t u3 = pu[(size_t)i3 * 8 + sub];
            uint32_t u4 = pu[(size_t)i4 * 8 + sub];
            uint32_t u5 = pu[(size_t)i5 * 8 + sub];
            uint32_t u6 = pu[(size_t)i6 * 8 + sub];
            uint32_t u7 = pu[(size_t)i7 * 8 + sub];
            a0 += ((bflo(u0) + bflo(u1)) + (bflo(u2) + bflo(u3))) +
                  ((bflo(u4) + bflo(u5)) + (bflo(u6) + bflo(u7)));
            a1 += ((bfhi(u0) + bfhi(u1)) + (bfhi(u2) + bfhi(u3))) +
                  ((bfhi(u4) + bfhi(u5)) + (bfhi(u6) + bfhi(u7)));
        }
        if (valid) {
            float sc = 1.0f / (float)(d > 0 ? d : 1);
            uint32_t rv = ru[(size_t)n * 8 + sub];
            float o0 = fmaf(a0, sc, bflo(rv));
            float o1 = fmaf(a1, sc, bfhi(rv));
            bf16x2 ov = {(bf16)o0, (bf16)o1};
            *(bf16x2*)(ot + (size_t)n * 16 + sub * 2) = ov;
            s0 += o0;
            s1 += o1;
            q0 += o0 * o0;
            q1 += o1 * o1;
        }
    }
#pragma unroll
    for (int msk = 8; msk < 64; msk <<= 1) {
        s0 += __shfl_xor(s0, msk, 64);
        s1 += __shfl_xor(s1, msk, 64);
        q0 += __shfl_xor(q0, msk, 64);
        q1 += __shfl_xor(q1, msk, 64);
    }
    if (grp == 0) {
        int c = cg * 16 + sub * 2;
        atomicAdd(&ssum[c], s0);
        atomicAdd(&ssum[c + 1], s1);
        atomicAdd(&ssq[c], q0);
        atomicAdd(&ssq[c + 1], q1);
    }
}

// ---------------- BN finalize + final output ----------------

__global__ __launch_bounds__(128) void k_bn_fin(const float* __restrict__ ssum, const float* __restrict__ ssq,
                                                const float* __restrict__ gamma, const float* __restrict__ beta,
                                                float* __restrict__ cA, float* __restrict__ cB, int Cout, int N) {
    int c = threadIdx.x;
    if (c >= Cout) return;
    float m = ssum[c] / (float)N;
    float var = ssq[c] / (float)N - m * m;
    float a = gamma[c] * rsqrtf(var + 1e-5f);
    cA[c] = a;
    cB[c] = beta[c] - m * a;
}

// o (bf16 col-tiled, 4 groups, C=64) -> out (f32 row-major), affine, no relu
__global__ __launch_bounds__(256) void k_norm_out(const bf16* __restrict__ o, const float* __restrict__ cA,
                                                  const float* __restrict__ cB, float* __restrict__ out, int N) {
    int i = blockIdx.x * 256 + threadIdx.x;
    if (i >= N * 8) return;
    int n = i >> 3;
    int col0 = (i & 7) * 8;
    int g = col0 >> 4;
    int offs = col0 & 15;
    bf16x8 u = *(const bf16x8*)(o + (size_t)g * N * 16 + (size_t)n * 16 + offs);
    float4 ca0 = *(const float4*)(cA + col0);
    float4 ca1 = *(const float4*)(cA + col0 + 4);
    float4 cb0 = *(const float4*)(cB + col0);
    float4 cb1 = *(const float4*)(cB + col0 + 4);
    float4 w0, w1;
    w0.x = fmaf((float)u[0], ca0.x, cb0.x);
    w0.y = fmaf((float)u[1], ca0.y, cb0.y);
    w0.z = fmaf((float)u[2], ca0.z, cb0.z);
    w0.w = fmaf((float)u[3], ca0.w, cb0.w);
    w1.x = fmaf((float)u[4], ca1.x, cb1.x);
    w1.y = fmaf((float)u[5], ca1.y, cb1.y);
    w1.z = fmaf((float)u[6], ca1.z, cb1.z);
    w1.w = fmaf((float)u[7], ca1.w, cb1.w);
    *(float4*)(out + (size_t)n * 64 + col0) = w0;
    *(float4*)(out + (size_t)n * 64 + col0 + 4) = w1;
}

// ---------------- launch ----------------

static inline int cdiv(int a, int b) { return (a + b - 1) / b; }

extern "C" void kernel_launch(void* const* d_in, const int* in_sizes, int n_in,
                              void* d_out, int out_size, void* d_ws, size_t ws_size,
                              hipStream_t stream) {
    const float* x = (const float*)d_in[0];
    const int* ei = (const int*)d_in[1];
    const float* Wl[3] = {(const float*)d_in[2], (const float*)d_in[7], (const float*)d_in[12]};
    const float* bl[3] = {(const float*)d_in[3], (const float*)d_in[8], (const float*)d_in[13]};
    const float* Wr[3] = {(const float*)d_in[4], (const float*)d_in[9], (const float*)d_in[14]};
    const float* gam[3] = {(const float*)d_in[5], (const float*)d_in[10], (const float*)d_in[15]};
    const float* bet[3] = {(const float*)d_in[6], (const float*)d_in[11], (const float*)d_in[16]};

    const int N = in_sizes[0] / 128;  // 100000
    const int E = in_sizes[1] / 2;    // 1600000
    const int NP = N + 8;             // p slice rows (row N = zero row for pads)
    const int Ecap = E + 7 * ((N + 7) & ~7);
    const int Couts[3] = {128, 128, 64};

    char* base = (char*)d_ws;
    size_t off = 0;
    auto alloc = [&](size_t bytes) -> void* {
        void* ptr = base + off;
        off += (bytes + 255) & ~(size_t)255;
        return ptr;
    };
    bf16* p = (bf16*)alloc((size_t)8 * NP * 16 * 2);
    bf16* r = (bf16*)alloc((size_t)N * 128 * 2);
    bf16* o = (bf16*)alloc((size_t)N * 128 * 2);
    bf16* w0 = (bf16*)alloc(2 * 128 * 128 * 2);
    bf16* w1 = (bf16*)alloc(2 * 128 * 128 * 2);
    bf16* w2 = (bf16*)alloc(2 * 64 * 128 * 2);
    float* stats = (float*)alloc(3 * 512 * 4);
    int* rowptr = (int*)alloc((size_t)(N + 1) * 4);
    int* deg = (int*)alloc((size_t)N * 4);
    int* cursor = (int*)alloc((size_t)N * 4);
    int* bsum = (int*)alloc(512 * 4);
    int* ssrc = (int*)alloc((size_t)Ecap * 4);
    bf16* Wc[3] = {w0, w1, w2};

    const int* esrc = ei;
    const int* edst = ei + E;

    k_init<<<cdiv(Ecap, 256), 256, 0, stream>>>(deg, stats, p, ssrc, N, NP, Ecap);
    k_cvt_w<<<cdiv(128 * 128, 256), 256, 0, stream>>>(Wl[0], Wr[0], w0, 128 * 128);
    k_cvt_w<<<cdiv(128 * 128, 256), 256, 0, stream>>>(Wl[1], Wr[1], w1, 128 * 128);
    k_cvt_w<<<cdiv(64 * 128, 256), 256, 0, stream>>>(Wl[2], Wr[2], w2, 64 * 128);

    k_count<<<cdiv(E, 256), 256, 0, stream>>>(edst, deg, E);
    int nb = cdiv(N + 1, 256);
    k_scan1<<<nb, 256, 0, stream>>>(deg, rowptr, bsum, N);
    k_scan2<<<1, 512, 0, stream>>>(bsum, nb);
    k_scan3<<<nb, 256, 0, stream>>>(rowptr, bsum, cursor, N);
    k_scatter<<<cdiv(E, 256), 256, 0, stream>>>(esrc, edst, cursor, ssrc, E);

    const int AGG_BLOCKS = 2048;
    const int GEMM_BLOCKS = cdiv(N, 64);
    for (int l = 0; l < 3; l++) {
        int Cout = Couts[l];
        float* ss = stats + l * 512;
        float* sq = ss + 128;
        float* cA = ss + 256;
        float* cB = ss + 384;
        if (l == 0) {
            k_gemm<0><<<GEMM_BLOCKS, 256, 0, stream>>>(x, nullptr, nullptr, Wc[0], bl[0], p, r, Cout, N, NP);
        } else {
            float* pA = stats + (l - 1) * 512 + 256;
            float* pB = stats + (l - 1) * 512 + 384;
            k_gemm<1><<<GEMM_BLOCKS, 256, 0, stream>>>(o, pA, pB, Wc[l], bl[l], p, r, Cout, N, NP);
        }
        if (Cout == 128) {
            k_agg<8><<<AGG_BLOCKS, 256, 0, stream>>>(p, r, rowptr, deg, ssrc, o, ss, sq, N, NP);
        } else {
            k_agg<4><<<AGG_BLOCKS, 256, 0, stream>>>(p, r, rowptr, deg, ssrc, o, ss, sq, N, NP);
        }
        k_bn_fin<<<1, 128, 0, stream>>>(ss, sq, gam[l], bet[l], cA, cB, Cout, N);
        if (l == 2) {
            k_norm_out<<<cdiv(N * 8, 256), 256, 0, stream>>>(o, cA, cB, (float*)d_out, N);
        }
    }
}

// Round 5
// 758.602 us; speedup vs baseline: 7.0859x; 1.1009x over previous
//
#include <hip/hip_runtime.h>
#include <stdint.h>

typedef __bf16 bf16;
typedef __bf16 bf16x8 __attribute__((ext_vector_type(8)));
typedef __bf16 bf16x4 __attribute__((ext_vector_type(4)));
typedef __bf16 bf16x2 __attribute__((ext_vector_type(2)));
typedef float f32x4 __attribute__((ext_vector_type(4)));

static __device__ __forceinline__ float bflo(uint32_t u) { return __uint_as_float(u << 16); }
static __device__ __forceinline__ float bfhi(uint32_t u) { return __uint_as_float(u & 0xffff0000u); }

// ---------------- init ----------------

__global__ __launch_bounds__(256) void k_init(int* __restrict__ deg, float* __restrict__ stats,
                                              bf16* __restrict__ p, int* __restrict__ ssrc,
                                              int N, int NP, int Ecap) {
    int i = blockIdx.x * 256 + threadIdx.x;
    if (i < N) deg[i] = 0;
    if (i < 3 * 512) stats[i] = 0.f;
    if (i < Ecap) ssrc[i] = N;  // pad -> zero row
    if (i < 128) {
        int g = i >> 4, c = i & 15;
        p[(size_t)g * NP * 16 + (size_t)N * 16 + c] = (bf16)0.f;
    }
}

__global__ __launch_bounds__(256) void k_cvt_w(const float* __restrict__ wl, const float* __restrict__ wr,
                                               bf16* __restrict__ dst, int n) {
    int i = blockIdx.x * 256 + threadIdx.x;
    if (i >= n) return;
    dst[i] = (bf16)wl[i];
    dst[n + i] = (bf16)wr[i];
}

// ---------------- CSR build (XCD-sharded by dst range) ----------------
// blockIdx&7 -> shard g handling dst in [g*B, g*B+B). Each shard streams all E
// edges (int4); atomics + scatter writes stay in the local XCD L2 slice.

__global__ __launch_bounds__(256) void k_count(const int* __restrict__ dst, int* __restrict__ deg,
                                               int E, int B) {
    int g = blockIdx.x & 7;
    int lo = g * B, hi = lo + B;
    int br = blockIdx.x >> 3;
    int nb = gridDim.x >> 3;
    const int4* d4 = (const int4*)dst;
    int E4 = E >> 2;
    for (int i = br * 256 + threadIdx.x; i < E4; i += nb * 256) {
        int4 d = d4[i];
        if (d.x >= lo && d.x < hi) atomicAdd(&deg[d.x], 1);
        if (d.y >= lo && d.y < hi) atomicAdd(&deg[d.y], 1);
        if (d.z >= lo && d.z < hi) atomicAdd(&deg[d.z], 1);
        if (d.w >= lo && d.w < hi) atomicAdd(&deg[d.w], 1);
    }
}

__global__ __launch_bounds__(256) void k_scan1(const int* __restrict__ deg, int* __restrict__ rowptr,
                                               int* __restrict__ bsum, int N) {
    __shared__ int sh[256];
    int i = blockIdx.x * 256 + threadIdx.x;
    int v = (i < N) ? ((deg[i] + 7) & ~7) : 0;
    sh[threadIdx.x] = v;
    for (int off = 1; off < 256; off <<= 1) {
        __syncthreads();
        int t = (threadIdx.x >= off) ? sh[threadIdx.x - off] : 0;
        __syncthreads();
        sh[threadIdx.x] += t;
    }
    __syncthreads();
    if (i <= N) rowptr[i] = sh[threadIdx.x] - v;
    if (threadIdx.x == 255) bsum[blockIdx.x] = sh[255];
}

__global__ __launch_bounds__(512) void k_scan2(int* __restrict__ bsum, int nb) {
    __shared__ int sh[512];
    int v = (threadIdx.x < nb) ? bsum[threadIdx.x] : 0;
    sh[threadIdx.x] = v;
    for (int off = 1; off < 512; off <<= 1) {
        __syncthreads();
        int t = (threadIdx.x >= off) ? sh[threadIdx.x - off] : 0;
        __syncthreads();
        sh[threadIdx.x] += t;
    }
    __syncthreads();
    if (threadIdx.x < nb) bsum[threadIdx.x] = sh[threadIdx.x] - v;
}

__global__ __launch_bounds__(256) void k_scan3(int* __restrict__ rowptr, const int* __restrict__ bsum,
                                               int* __restrict__ cursor, int N) {
    int i = blockIdx.x * 256 + threadIdx.x;
    if (i <= N) {
        int v = rowptr[i] + bsum[i >> 8];
        rowptr[i] = v;
        if (i < N) cursor[i] = v;
    }
}

__global__ __launch_bounds__(256) void k_scatter(const int* __restrict__ src, const int* __restrict__ dst,
                                                 int* __restrict__ cursor, int* __restrict__ ssrc,
                                                 int E, int B) {
    int g = blockIdx.x & 7;
    int lo = g * B, hi = lo + B;
    int br = blockIdx.x >> 3;
    int nb = gridDim.x >> 3;
    const int4* d4 = (const int4*)dst;
    int E4 = E >> 2;
    for (int i = br * 256 + threadIdx.x; i < E4; i += nb * 256) {
        int4 d = d4[i];
        int e = i * 4;
        if (d.x >= lo && d.x < hi) { int pos = atomicAdd(&cursor[d.x], 1); ssrc[pos] = src[e]; }
        if (d.y >= lo && d.y < hi) { int pos = atomicAdd(&cursor[d.y], 1); ssrc[pos] = src[e + 1]; }
        if (d.z >= lo && d.z < hi) { int pos = atomicAdd(&cursor[d.z], 1); ssrc[pos] = src[e + 2]; }
        if (d.w >= lo && d.w < hi) { int pos = atomicAdd(&cursor[d.w], 1); ssrc[pos] = src[e + 3]; }
    }
}

// ---------------- fused GEMM ----------------
// MODE 0: A = x (f32 row-major). MODE 1: A = relu(o*cA+cB), o bf16 col-tiled.
// Out: P_t[g][NP][16] bf16, R_t[g][N][16] bf16 (= X@Wr^T + bl).

template <int MODE>
__global__ __launch_bounds__(256) void k_gemm(const void* __restrict__ srcv, const float* __restrict__ cA,
                                              const float* __restrict__ cB, const bf16* __restrict__ W,
                                              const float* __restrict__ bl, bf16* __restrict__ P,
                                              bf16* __restrict__ R, int Cout, int N, int NP) {
    int wv = blockIdx.x * 4 + (threadIdx.x >> 6);
    int lane = threadIdx.x & 63;
    int node0 = wv * 16;
    if (node0 >= N) return;
    int m = lane & 15, quad = lane >> 4;
    bf16x8 a[4];
    if (MODE == 0) {
        const float* x = (const float*)srcv;
        const float* xr = x + (size_t)(node0 + m) * 128 + quad * 8;
#pragma unroll
        for (int t = 0; t < 4; t++) {
            float4 v0 = *(const float4*)(xr + t * 32);
            float4 v1 = *(const float4*)(xr + t * 32 + 4);
            bf16x8 f = {(bf16)v0.x, (bf16)v0.y, (bf16)v0.z, (bf16)v0.w,
                        (bf16)v1.x, (bf16)v1.y, (bf16)v1.z, (bf16)v1.w};
            a[t] = f;
        }
    } else {
        const bf16* o = (const bf16*)srcv;
#pragma unroll
        for (int t = 0; t < 4; t++) {
            int col0 = t * 32 + quad * 8;
            int g = col0 >> 4;
            int offs = col0 & 15;
            bf16x8 u = *(const bf16x8*)(o + (size_t)g * N * 16 + (size_t)(node0 + m) * 16 + offs);
            float4 ca0 = *(const float4*)(cA + col0);
            float4 ca1 = *(const float4*)(cA + col0 + 4);
            float4 cb0 = *(const float4*)(cB + col0);
            float4 cb1 = *(const float4*)(cB + col0 + 4);
            float h0 = fmaxf(fmaf((float)u[0], ca0.x, cb0.x), 0.f);
            float h1 = fmaxf(fmaf((float)u[1], ca0.y, cb0.y), 0.f);
            float h2 = fmaxf(fmaf((float)u[2], ca0.z, cb0.z), 0.f);
            float h3 = fmaxf(fmaf((float)u[3], ca0.w, cb0.w), 0.f);
            float h4 = fmaxf(fmaf((float)u[4], ca1.x, cb1.x), 0.f);
            float h5 = fmaxf(fmaf((float)u[5], ca1.y, cb1.y), 0.f);
            float h6 = fmaxf(fmaf((float)u[6], ca1.z, cb1.z), 0.f);
            float h7 = fmaxf(fmaf((float)u[7], ca1.w, cb1.w), 0.f);
            bf16x8 f = {(bf16)h0, (bf16)h1, (bf16)h2, (bf16)h3,
                        (bf16)h4, (bf16)h5, (bf16)h6, (bf16)h7};
            a[t] = f;
        }
    }
    int ntiles = (2 * Cout) >> 4;
    int ntilesP = Cout >> 4;
    for (int ct = 0; ct < ntiles; ct++) {
        const bf16* wr = W + (size_t)(ct * 16 + m) * 128 + quad * 8;
        f32x4 acc = {0.f, 0.f, 0.f, 0.f};
        acc = __builtin_amdgcn_mfma_f32_16x16x32_bf16(a[0], *(const bf16x8*)(wr), acc, 0, 0, 0);
        acc = __builtin_amdgcn_mfma_f32_16x16x32_bf16(a[1], *(const bf16x8*)(wr + 32), acc, 0, 0, 0);
        acc = __builtin_amdgcn_mfma_f32_16x16x32_bf16(a[2], *(const bf16x8*)(wr + 64), acc, 0, 0, 0);
        acc = __builtin_amdgcn_mfma_f32_16x16x32_bf16(a[3], *(const bf16x8*)(wr + 96), acc, 0, 0, 0);
        if (ct < ntilesP) {
            bf16* pp = P + (size_t)ct * NP * 16 + (size_t)(node0 + quad * 4) * 16 + m;
            pp[0] = (bf16)acc[0];
            pp[16] = (bf16)acc[1];
            pp[32] = (bf16)acc[2];
            pp[48] = (bf16)acc[3];
        } else {
            int gt = ct - ntilesP;
            float bb = bl[gt * 16 + m];
            bf16* rr = R + (size_t)gt * N * 16 + (size_t)(node0 + quad * 4) * 16 + m;
            rr[0] = (bf16)(acc[0] + bb);
            rr[16] = (bf16)(acc[1] + bb);
            rr[32] = (bf16)(acc[2] + bb);
            rr[48] = (bf16)(acc[3] + bb);
        }
    }
}

// ---------------- aggregate (XCD-sharded, node-per-group, index prefetch) ----------------

template <int NG>
__global__ __launch_bounds__(256, 8) void k_agg(const bf16* __restrict__ p, const bf16* __restrict__ r,
                                                const int* __restrict__ rowptr, const int* __restrict__ deg,
                                                const int* __restrict__ ssrc, bf16* __restrict__ o,
                                                float* __restrict__ ssum, float* __restrict__ ssq,
                                                int N, int NP) {
    int g = blockIdx.x & 7;
    int cg = g % NG;
    constexpr int NREP = 8 / NG;
    int rep = g / NG;
    int wvr = ((blockIdx.x >> 3) * NREP + rep) * 4 + (threadIdx.x >> 6);
    int nwv = (gridDim.x >> 3) * NREP * 4;
    int lane = threadIdx.x & 63;
    int sub = lane & 7;
    int grp = lane >> 3;
    const uint32_t* pu = (const uint32_t*)(p + (size_t)cg * NP * 16);
    const uint32_t* ru = (const uint32_t*)(r + (size_t)cg * N * 16);
    bf16* ot = o + (size_t)cg * N * 16;
    float s0 = 0.f, s1 = 0.f, q0 = 0.f, q1 = 0.f;
    int nchunk = (N + 7) >> 3;
    for (int c = wvr; c < nchunk; c += nwv) {
        int n = c * 8 + grp;
        bool valid = n < N;
        int e = 0, iters = 0, d = 1;
        if (valid) {
            e = rowptr[n];
            iters = (rowptr[n + 1] - e) >> 3;
            d = deg[n];
        }
        float a0 = 0.f, a1 = 0.f;
        auto gather8 = [&](int i0, int i1, int i2, int i3, int i4, int i5, int i6, int i7) {
            uint32_t u0 = pu[(size_t)i0 * 8 + sub];
            uint32_t u1 = pu[(size_t)i1 * 8 + sub];
            uint32_t u2 = pu[(size_t)i2 * 8 + sub];
            uint32_t u3 = pu[(size_t)i3 * 8 + sub];
            uint32_t u4 = pu[(size_t)i4 * 8 + sub];
            uint32_t u5 = pu[(size_t)i5 * 8 + sub];
            uint32_t u6 = pu[(size_t)i6 * 8 + sub];
            uint32_t u7 = pu[(size_t)i7 * 8 + sub];
            a0 += ((bflo(u0) + bflo(u1)) + (bflo(u2) + bflo(u3))) +
                  ((bflo(u4) + bflo(u5)) + (bflo(u6) + bflo(u7)));
            a1 += ((bfhi(u0) + bfhi(u1)) + (bfhi(u2) + bfhi(u3))) +
                  ((bfhi(u4) + bfhi(u5)) + (bfhi(u6) + bfhi(u7)));
        };
        if (iters > 0) {
            const int* sp = ssrc + e;
            int i0 = sp[0], i1 = sp[1], i2 = sp[2], i3 = sp[3];
            int i4 = sp[4], i5 = sp[5], i6 = sp[6], i7 = sp[7];
            for (int t = 1; t < iters; t++) {
                sp += 8;
                int j0 = sp[0], j1 = sp[1], j2 = sp[2], j3 = sp[3];
                int j4 = sp[4], j5 = sp[5], j6 = sp[6], j7 = sp[7];
                gather8(i0, i1, i2, i3, i4, i5, i6, i7);
                i0 = j0; i1 = j1; i2 = j2; i3 = j3;
                i4 = j4; i5 = j5; i6 = j6; i7 = j7;
            }
            gather8(i0, i1, i2, i3, i4, i5, i6, i7);
        }
        if (valid) {
            float sc = 1.0f / (float)(d > 0 ? d : 1);
            uint32_t rv = ru[(size_t)n * 8 + sub];
            float o0 = fmaf(a0, sc, bflo(rv));
            float o1 = fmaf(a1, sc, bfhi(rv));
            bf16x2 ov = {(bf16)o0, (bf16)o1};
            *(bf16x2*)(ot + (size_t)n * 16 + sub * 2) = ov;
            s0 += o0;
            s1 += o1;
            q0 += o0 * o0;
            q1 += o1 * o1;
        }
    }
#pragma unroll
    for (int msk = 8; msk < 64; msk <<= 1) {
        s0 += __shfl_xor(s0, msk, 64);
        s1 += __shfl_xor(s1, msk, 64);
        q0 += __shfl_xor(q0, msk, 64);
        q1 += __shfl_xor(q1, msk, 64);
    }
    if (grp == 0) {
        int c = cg * 16 + sub * 2;
        atomicAdd(&ssum[c], s0);
        atomicAdd(&ssum[c + 1], s1);
        atomicAdd(&ssq[c], q0);
        atomicAdd(&ssq[c + 1], q1);
    }
}

// ---------------- BN finalize + final output ----------------

__global__ __launch_bounds__(128) void k_bn_fin(const float* __restrict__ ssum, const float* __restrict__ ssq,
                                                const float* __restrict__ gamma, const float* __restrict__ beta,
                                                float* __restrict__ cA, float* __restrict__ cB, int Cout, int N) {
    int c = threadIdx.x;
    if (c >= Cout) return;
    float m = ssum[c] / (float)N;
    float var = ssq[c] / (float)N - m * m;
    float a = gamma[c] * rsqrtf(var + 1e-5f);
    cA[c] = a;
    cB[c] = beta[c] - m * a;
}

__global__ __launch_bounds__(256) void k_norm_out(const bf16* __restrict__ o, const float* __restrict__ cA,
                                                  const float* __restrict__ cB, float* __restrict__ out, int N) {
    int i = blockIdx.x * 256 + threadIdx.x;
    if (i >= N * 8) return;
    int n = i >> 3;
    int col0 = (i & 7) * 8;
    int g = col0 >> 4;
    int offs = col0 & 15;
    bf16x8 u = *(const bf16x8*)(o + (size_t)g * N * 16 + (size_t)n * 16 + offs);
    float4 ca0 = *(const float4*)(cA + col0);
    float4 ca1 = *(const float4*)(cA + col0 + 4);
    float4 cb0 = *(const float4*)(cB + col0);
    float4 cb1 = *(const float4*)(cB + col0 + 4);
    float4 w0, w1;
    w0.x = fmaf((float)u[0], ca0.x, cb0.x);
    w0.y = fmaf((float)u[1], ca0.y, cb0.y);
    w0.z = fmaf((float)u[2], ca0.z, cb0.z);
    w0.w = fmaf((float)u[3], ca0.w, cb0.w);
    w1.x = fmaf((float)u[4], ca1.x, cb1.x);
    w1.y = fmaf((float)u[5], ca1.y, cb1.y);
    w1.z = fmaf((float)u[6], ca1.z, cb1.z);
    w1.w = fmaf((float)u[7], ca1.w, cb1.w);
    *(float4*)(out + (size_t)n * 64 + col0) = w0;
    *(float4*)(out + (size_t)n * 64 + col0 + 4) = w1;
}

// ---------------- launch ----------------

static inline int cdiv(int a, int b) { return (a + b - 1) / b; }

extern "C" void kernel_launch(void* const* d_in, const int* in_sizes, int n_in,
                              void* d_out, int out_size, void* d_ws, size_t ws_size,
                              hipStream_t stream) {
    const float* x = (const float*)d_in[0];
    const int* ei = (const int*)d_in[1];
    const float* Wl[3] = {(const float*)d_in[2], (const float*)d_in[7], (const float*)d_in[12]};
    const float* bl[3] = {(const float*)d_in[3], (const float*)d_in[8], (const float*)d_in[13]};
    const float* Wr[3] = {(const float*)d_in[4], (const float*)d_in[9], (const float*)d_in[14]};
    const float* gam[3] = {(const float*)d_in[5], (const float*)d_in[10], (const float*)d_in[15]};
    const float* bet[3] = {(const float*)d_in[6], (const float*)d_in[11], (const float*)d_in[16]};

    const int N = in_sizes[0] / 128;  // 100000
    const int E = in_sizes[1] / 2;    // 1600000
    const int NP = N + 8;
    const int Ecap = E + 7 * ((N + 7) & ~7);
    const int B = (N + 7) / 8;  // dst-range bucket per XCD
    const int Couts[3] = {128, 128, 64};

    char* base = (char*)d_ws;
    size_t off = 0;
    auto alloc = [&](size_t bytes) -> void* {
        void* ptr = base + off;
        off += (bytes + 255) & ~(size_t)255;
        return ptr;
    };
    bf16* p = (bf16*)alloc((size_t)8 * NP * 16 * 2);
    bf16* r = (bf16*)alloc((size_t)N * 128 * 2);
    bf16* o = (bf16*)alloc((size_t)N * 128 * 2);
    bf16* w0 = (bf16*)alloc(2 * 128 * 128 * 2);
    bf16* w1 = (bf16*)alloc(2 * 128 * 128 * 2);
    bf16* w2 = (bf16*)alloc(2 * 64 * 128 * 2);
    float* stats = (float*)alloc(3 * 512 * 4);
    int* rowptr = (int*)alloc((size_t)(N + 1) * 4);
    int* deg = (int*)alloc((size_t)N * 4);
    int* cursor = (int*)alloc((size_t)N * 4);
    int* bsum = (int*)alloc(512 * 4);
    int* ssrc = (int*)alloc((size_t)Ecap * 4);
    bf16* Wc[3] = {w0, w1, w2};

    const int* esrc = ei;
    const int* edst = ei + E;

    k_init<<<cdiv(Ecap, 256), 256, 0, stream>>>(deg, stats, p, ssrc, N, NP, Ecap);
    k_cvt_w<<<cdiv(128 * 128, 256), 256, 0, stream>>>(Wl[0], Wr[0], w0, 128 * 128);
    k_cvt_w<<<cdiv(128 * 128, 256), 256, 0, stream>>>(Wl[1], Wr[1], w1, 128 * 128);
    k_cvt_w<<<cdiv(64 * 128, 256), 256, 0, stream>>>(Wl[2], Wr[2], w2, 64 * 128);

    k_count<<<2048, 256, 0, stream>>>(edst, deg, E, B);
    int nb = cdiv(N + 1, 256);
    k_scan1<<<nb, 256, 0, stream>>>(deg, rowptr, bsum, N);
    k_scan2<<<1, 512, 0, stream>>>(bsum, nb);
    k_scan3<<<nb, 256, 0, stream>>>(rowptr, bsum, cursor, N);
    k_scatter<<<2048, 256, 0, stream>>>(esrc, edst, cursor, ssrc, E, B);

    const int AGG_BLOCKS = 2048;
    const int GEMM_BLOCKS = cdiv(N, 64);
    for (int l = 0; l < 3; l++) {
        int Cout = Couts[l];
        float* ss = stats + l * 512;
        float* sq = ss + 128;
        float* cA = ss + 256;
        float* cB = ss + 384;
        if (l == 0) {
            k_gemm<0><<<GEMM_BLOCKS, 256, 0, stream>>>(x, nullptr, nullptr, Wc[0], bl[0], p, r, Cout, N, NP);
        } else {
            float* pA = stats + (l - 1) * 512 + 256;
            float* pB = stats + (l - 1) * 512 + 384;
            k_gemm<1><<<GEMM_BLOCKS, 256, 0, stream>>>(o, pA, pB, Wc[l], bl[l], p, r, Cout, N, NP);
        }
        if (Cout == 128) {
            k_agg<8><<<AGG_BLOCKS, 256, 0, stream>>>(p, r, rowptr, deg, ssrc, o, ss, sq, N, NP);
        } else {
            k_agg<4><<<AGG_BLOCKS, 256, 0, stream>>>(p, r, rowptr, deg, ssrc, o, ss, sq, N, NP);
        }
        k_bn_fin<<<1, 128, 0, stream>>>(ss, sq, gam[l], bet[l], cA, cB, Cout, N);
        if (l == 2) {
            k_norm_out<<<cdiv(N * 8, 256), 256, 0, stream>>>(o, cA, cB, (float*)d_out, N);
        }
    }
}